// Round 1
// baseline (995.115 us; speedup 1.0000x reference)
//
#include <hip/hip_runtime.h>

// Problem constants (from reference)
#define B_DIM 8
#define NP 81920
#define DL 16
#define DA 4
#define DT_TOTAL 20          // DL + DA
#define H_DIM 128
#define NB 3
#define FAN_IN (NB * DT_TOTAL)   // 60
#define DT_STEP 0.1f
#define BLOCK 256

// fast tanh via exp2-based expf; error ~1e-6, fine vs 0.116 threshold
__device__ __forceinline__ float tanh_fast(float x) {
    float ax = fabsf(x);
    float e  = __expf(-2.0f * ax);          // in (0,1]
    float t  = (1.0f - e) / (1.0f + e);     // tanh(|x|)
    return copysignf(t, x);
}

// One Euler step: Yout = Yin with [:, :, :DL] += DT * Phi(gather(Yin))
// One thread per (b,p). W1 (transposed) + W2 + biases staged in LDS;
// per-j column reads are wave-uniform broadcasts (conflict-free).
__global__ __launch_bounds__(BLOCK) void neural_step(
    const float* __restrict__ Yin,
    float*       __restrict__ Yout,
    const int*   __restrict__ nbr,     // [NP][NB] int32
    const float* __restrict__ W1,      // [FAN_IN][H]
    const float* __restrict__ b1,      // [H]
    const float* __restrict__ W2,      // [H][DL]
    const float* __restrict__ b2)      // [DL]
{
    __shared__ float sW1t[H_DIM * FAN_IN];  // [j][k] (transposed), rows 240B -> float4 ok
    __shared__ float sW2 [H_DIM * DL];      // [j][d], rows 64B
    __shared__ float sb1 [H_DIM];
    __shared__ float sb2 [DL];

    // stage weights
    for (int i = threadIdx.x; i < H_DIM * FAN_IN; i += BLOCK) {
        int f = i / H_DIM;          // 0..59
        int h = i - f * H_DIM;      // 0..127
        sW1t[h * FAN_IN + f] = W1[i];
    }
    for (int i = threadIdx.x; i < H_DIM * DL; i += BLOCK) sW2[i] = W2[i];
    if (threadIdx.x < H_DIM) sb1[threadIdx.x] = b1[threadIdx.x];
    if (threadIdx.x < DL)    sb2[threadIdx.x] = b2[threadIdx.x];
    __syncthreads();

    const int tid = blockIdx.x * BLOCK + threadIdx.x;  // = b*NP + p
    const int b   = tid / NP;
    const int p   = tid - b * NP;

    const float* Yb = Yin + (size_t)b * NP * DT_TOTAL;

    // gather 3 neighbor rows -> zf[60] in registers (rows are 80B, 16B-aligned)
    float zf[FAN_IN];
    #pragma unroll
    for (int n = 0; n < NB; n++) {
        const int idx = nbr[p * NB + n];
        const float4* row = (const float4*)(Yb + (size_t)idx * DT_TOTAL);
        #pragma unroll
        for (int q = 0; q < DT_TOTAL / 4; q++) {
            float4 v = row[q];
            zf[n * DT_TOTAL + q * 4 + 0] = v.x;
            zf[n * DT_TOTAL + q * 4 + 1] = v.y;
            zf[n * DT_TOTAL + q * 4 + 2] = v.z;
            zf[n * DT_TOTAL + q * 4 + 3] = v.w;
        }
    }

    float fz[DL];
    #pragma unroll
    for (int d = 0; d < DL; d++) fz[d] = sb2[d];

    // MLP: for each hidden unit j, dot(zf, W1[:,j]) -> tanh -> accumulate into fz
    #pragma unroll 2
    for (int j = 0; j < H_DIM; j++) {
        float acc = sb1[j];
        const float4* w1 = (const float4*)(sW1t + j * FAN_IN);
        #pragma unroll
        for (int kk = 0; kk < FAN_IN / 4; kk++) {
            float4 w = w1[kk];
            acc = fmaf(zf[kk * 4 + 0], w.x, acc);
            acc = fmaf(zf[kk * 4 + 1], w.y, acc);
            acc = fmaf(zf[kk * 4 + 2], w.z, acc);
            acc = fmaf(zf[kk * 4 + 3], w.w, acc);
        }
        const float hj = tanh_fast(acc);
        const float4* w2 = (const float4*)(sW2 + j * DL);
        #pragma unroll
        for (int dd = 0; dd < DL / 4; dd++) {
            float4 w = w2[dd];
            fz[dd * 4 + 0] = fmaf(hj, w.x, fz[dd * 4 + 0]);
            fz[dd * 4 + 1] = fmaf(hj, w.y, fz[dd * 4 + 1]);
            fz[dd * 4 + 2] = fmaf(hj, w.z, fz[dd * 4 + 2]);
            fz[dd * 4 + 3] = fmaf(hj, w.w, fz[dd * 4 + 3]);
        }
    }

    // own row: first 16 get += DT*fz, last 4 copied through
    const float4* own  = (const float4*)(Yb + (size_t)p * DT_TOTAL);
    float4*       outp = (float4*)(Yout + ((size_t)b * NP + p) * DT_TOTAL);
    #pragma unroll
    for (int q = 0; q < DL / 4; q++) {
        float4 o = own[q];
        o.x = fmaf(DT_STEP, fz[q * 4 + 0], o.x);
        o.y = fmaf(DT_STEP, fz[q * 4 + 1], o.y);
        o.z = fmaf(DT_STEP, fz[q * 4 + 2], o.z);
        o.w = fmaf(DT_STEP, fz[q * 4 + 3], o.w);
        outp[q] = o;
    }
    outp[4] = own[4];  // DA channels pass through
}

extern "C" void kernel_launch(void* const* d_in, const int* in_sizes, int n_in,
                              void* d_out, int out_size, void* d_ws, size_t ws_size,
                              hipStream_t stream) {
    const float* inputs = (const float*)d_in[0];
    const int*   nbr    = (const int*)  d_in[1];
    const float* W1     = (const float*)d_in[2];
    const float* b1     = (const float*)d_in[3];
    const float* W2     = (const float*)d_in[4];
    const float* b2     = (const float*)d_in[5];
    float* out = (float*)d_out;
    float* ws  = (float*)d_ws;   // needs B*NP*DT_TOTAL*4 = 52.4 MB; fully rewritten every step

    const dim3 grid(B_DIM * NP / BLOCK), block(BLOCK);
    // 4 Euler steps with global dependency between steps -> 4 launches, ping-pong
    neural_step<<<grid, block, 0, stream>>>(inputs, ws,  nbr, W1, b1, W2, b2);
    neural_step<<<grid, block, 0, stream>>>(ws,     out, nbr, W1, b1, W2, b2);
    neural_step<<<grid, block, 0, stream>>>(out,    ws,  nbr, W1, b1, W2, b2);
    neural_step<<<grid, block, 0, stream>>>(ws,     out, nbr, W1, b1, W2, b2);
}

// Round 2
// 375.736 us; speedup vs baseline: 2.6484x; 2.6484x over previous
//
#include <hip/hip_runtime.h>

// Problem constants
#define B_DIM 8
#define NPTS  81920
#define DL    16
#define DTOT  20          // DL + DA
#define HD    128
#define NB    3
#define DT_STEP 0.1f

#define BLOCK 256
#define GRID  1280
#define ITERS 8           // GRID * ITERS * 64 = 655360 points

typedef __attribute__((ext_vector_type(8))) short short8;  // 8 bf16 (4 VGPRs)
typedef __attribute__((ext_vector_type(4))) float f32x4;   // MFMA acc

// ---- LDS layout (bytes) ----
// main loop:  h tiles  [0, 17408)   : per-wave 16 x 136 shorts (272 B rows)
//             A tiles  [18432,27648): per-wave 16 x 72  shorts (144 B rows)
// phase 0:    W1T      [0, 18432)   : 128 x 72 shorts  (overlaps h — barrier-separated)
//             W2T      [18432,22784): 16 x 136 shorts  (overlaps A — barrier-separated)
#define H_BASE   0
#define A_BASE   18432
#define W2T_BASE 18432
#define SMEM_BYTES 27648

__device__ __forceinline__ unsigned short f2bf(float f) {
    unsigned u = __builtin_bit_cast(unsigned, f);
    u += 0x7FFFu + ((u >> 16) & 1u);           // RNE
    return (unsigned short)(u >> 16);
}
__device__ __forceinline__ unsigned pack2(float a, float b) {
    return (unsigned)f2bf(a) | ((unsigned)f2bf(b) << 16);
}
__device__ __forceinline__ float tanh_fast(float x) {
    // tanh(x) = (1 - e^-2x) / (1 + e^-2x); e^-2x = 2^(x * -2/ln2)
    float e = __builtin_amdgcn_exp2f(x * -2.885390082f);
    e = fminf(e, 1e30f);                       // kill inf -> exact -1
    float r = __builtin_amdgcn_rcpf(1.0f + e);
    return (1.0f - e) * r;
}

__global__ __launch_bounds__(BLOCK, 3) void neural_step_mfma(
    const float* __restrict__ Yin, float* __restrict__ Yout,
    const int*   __restrict__ nbr,
    const float* __restrict__ W1, const float* __restrict__ b1,
    const float* __restrict__ W2, const float* __restrict__ b2)
{
    __shared__ __align__(16) char smem[SMEM_BYTES];
    const int t = threadIdx.x;

    // ---- phase 0: stage W1^T [n][k] and W2^T [d][k] as bf16, pull fragments to regs ----
    unsigned short* sW1T = (unsigned short*)smem;
    for (int f = t; f < 60 * 128; f += BLOCK) {        // W1[k][n] -> sW1T[n][k]
        int k = f >> 7, n = f & 127;
        sW1T[n * 72 + k] = f2bf(W1[f]);
    }
    for (int f = t; f < 128 * 4; f += BLOCK) {         // zero-pad k = 60..63
        int n = f >> 2;
        sW1T[n * 72 + 60 + (f & 3)] = 0;
    }
    unsigned short* sW2T = (unsigned short*)(smem + W2T_BASE);
    for (int f = t; f < 128 * 16; f += BLOCK) {        // W2[k][d] -> sW2T[d][k]
        int k = f >> 4, d = f & 15;
        sW2T[d * 136 + k] = f2bf(W2[f]);
    }
    __syncthreads();

    const int lane = t & 63, w = t >> 6;
    const int l15 = lane & 15, q = lane >> 4;

    // B1 fragments: B[k][n], n = l15 + 16*nt, k = ks*32 + q*8 + j
    short8 B1f[8][2];
    #pragma unroll
    for (int nt = 0; nt < 8; nt++)
        #pragma unroll
        for (int ks = 0; ks < 2; ks++)
            B1f[nt][ks] = *(const short8*)(sW1T + (nt * 16 + l15) * 72 + ks * 32 + q * 8);
    // W2^T A'-fragments: A'[d][k], d = l15, k = ks*32 + q*8 + j
    short8 W2f[4];
    #pragma unroll
    for (int ks = 0; ks < 4; ks++)
        W2f[ks] = *(const short8*)(sW2T + l15 * 136 + ks * 32 + q * 8);
    float b1v[8];
    #pragma unroll
    for (int nt = 0; nt < 8; nt++) b1v[nt] = b1[nt * 16 + l15];
    const f32x4 b2v = *(const f32x4*)(b2 + q * 4);
    __syncthreads();   // weights in regs; LDS now reusable for A / h

    // ---- work assignment: XCD-swizzled so each XCD owns one batch b (L2 locality) ----
    const int bk  = blockIdx.x;
    const int bB  = bk & 7;                      // batch
    const int p0blk = (bk >> 3) * (ITERS * 64);  // point offset within batch
    const float* Ybase = Yin + (size_t)bB * NPTS * DTOT;

    unsigned short* hrow  = (unsigned short*)(smem + H_BASE + w * 4352);
    const char*     Atile = smem + A_BASE + w * 2304;

    for (int it = 0; it < ITERS; it++) {
        const int p0 = p0blk + it * 64;

        // ---- stage A: 64 points x 3 nbr rows, fp32 -> bf16 into [16][72] tiles ----
        if (t < 192) {
            const int i = t / 3, n = t - i * 3;  // local point, neighbour slot
            const int idx = nbr[p0 * 3 + t];     // coalesced
            const float4* src = (const float4*)(Ybase + (size_t)idx * DTOT);
            char* dst = smem + A_BASE + (i >> 4) * 2304 + (i & 15) * 144 + n * 40;
            #pragma unroll
            for (int c = 0; c < 5; c++) {
                float4 v = src[c];
                uint2 pk; pk.x = pack2(v.x, v.y); pk.y = pack2(v.z, v.w);
                *(uint2*)(dst + c * 8) = pk;
            }
        } else {
            const int r = t - 192;               // zero-pad k = 60..63 per row
            uint2 z; z.x = 0; z.y = 0;
            *(uint2*)(smem + A_BASE + (r >> 4) * 2304 + (r & 15) * 144 + 120) = z;
        }
        __syncthreads();
        // A fragments: A[m][k], m = l15, k = q*8 + j (+32)
        short8 a0 = *(const short8*)(Atile + l15 * 144 + q * 16);
        short8 a1 = *(const short8*)(Atile + l15 * 144 + 64 + q * 16);
        __syncthreads();   // all waves have their A frags; LDS A free for next iter

        // ---- layer 1: D[m][n] col=l15(n), row=q*4+r(m); tanh; h -> LDS [m][k] bf16 ----
        #pragma unroll
        for (int nt = 0; nt < 8; nt++) {
            f32x4 acc = { b1v[nt], b1v[nt], b1v[nt], b1v[nt] };
            acc = __builtin_amdgcn_mfma_f32_16x16x32_bf16(a0, B1f[nt][0], acc, 0, 0, 0);
            acc = __builtin_amdgcn_mfma_f32_16x16x32_bf16(a1, B1f[nt][1], acc, 0, 0, 0);
            #pragma unroll
            for (int r = 0; r < 4; r++)
                hrow[(q * 4 + r) * 136 + nt * 16 + l15] = f2bf(tanh_fast(acc[r]));
        }

        // ---- layer 2 (transposed): E[d][m] = W2^T @ h^T; col=l15 -> point, row -> channel ----
        f32x4 acc2 = { b2v.x, b2v.y, b2v.z, b2v.w };   // b2[q*4+r]
        #pragma unroll
        for (int ks = 0; ks < 4; ks++) {
            short8 hb = *(const short8*)((const char*)hrow + l15 * 272 + ks * 64 + q * 16);
            acc2 = __builtin_amdgcn_mfma_f32_16x16x32_bf16(W2f[ks], hb, acc2, 0, 0, 0);
        }

        // ---- epilogue: lane owns point l15, channels q*4..q*4+3 (contiguous float4) ----
        const size_t row = (size_t)bB * NPTS + (size_t)(p0 + w * 16 + l15);
        float4 o = *(const float4*)(Yin + row * DTOT + q * 4);
        o.x += DT_STEP * acc2[0]; o.y += DT_STEP * acc2[1];
        o.z += DT_STEP * acc2[2]; o.w += DT_STEP * acc2[3];
        *(float4*)(Yout + row * DTOT + q * 4) = o;
        if (q == 0)   // DA pass-through channels 16..19
            *(float4*)(Yout + row * DTOT + 16) = *(const float4*)(Yin + row * DTOT + 16);
    }
}

extern "C" void kernel_launch(void* const* d_in, const int* in_sizes, int n_in,
                              void* d_out, int out_size, void* d_ws, size_t ws_size,
                              hipStream_t stream) {
    const float* inputs = (const float*)d_in[0];
    const int*   nbr    = (const int*)  d_in[1];
    const float* W1     = (const float*)d_in[2];
    const float* b1     = (const float*)d_in[3];
    const float* W2     = (const float*)d_in[4];
    const float* b2     = (const float*)d_in[5];
    float* out = (float*)d_out;
    float* ws  = (float*)d_ws;   // 52.4 MB ping-pong buffer, fully rewritten each step

    const dim3 grid(GRID), block(BLOCK);
    neural_step_mfma<<<grid, block, 0, stream>>>(inputs, ws,  nbr, W1, b1, W2, b2);
    neural_step_mfma<<<grid, block, 0, stream>>>(ws,     out, nbr, W1, b1, W2, b2);
    neural_step_mfma<<<grid, block, 0, stream>>>(out,    ws,  nbr, W1, b1, W2, b2);
    neural_step_mfma<<<grid, block, 0, stream>>>(ws,     out, nbr, W1, b1, W2, b2);
}